// Round 4
// baseline (423.349 us; speedup 1.0000x reference)
//
#include <hip/hip_runtime.h>
#include <math.h>

#define NTOT   65536
#define DDIM   256
#define BATCH  2048
#define NPREV  (NTOT - BATCH)   // 63488

#define NC_P 31
#define CHUNK_P 2048            // 31 * 2048 = 63488
#define NC_R 16
#define CHUNK_R 128             // 16 * 128 = 2048

#define INF_F 3.402823466e+38f
#define SWZ(r) ((((r) & 3)) ^ ((((r) >> 2) & 3)))

typedef float  f32x4 __attribute__((ext_vector_type(4)));
typedef _Float16 half8 __attribute__((ext_vector_type(8)));

// halves per 128-row tile image: 128 r * 256 k * 2 (hi,lo) = 65536
#define TILE_HALVES 65536
// halves per kb block within a tile: 2(hl) * 128 r * 4 s * 8 = 8192
#define KB_HALVES   8192

// ---------------- row norms (standalone, used by fallback) ----------------
__global__ void lp_norms(const float* __restrict__ lib, float* __restrict__ ln) {
    const int row  = blockIdx.x * 4 + (threadIdx.x >> 6);
    const int lane = threadIdx.x & 63;
    const float4 v = reinterpret_cast<const float4*>(lib + (size_t)row * DDIM)[lane];
    float s = v.x * v.x + v.y * v.y + v.z * v.z + v.w * v.w;
#pragma unroll
    for (int off = 32; off > 0; off >>= 1) s += __shfl_down(s, off);
    if (lane == 0) ln[row] = s;
}

// fp16 split with x256 scaling (keeps residual out of subnormal range)
__device__ __forceinline__ void cvt_split(const f32x4 a, const f32x4 b,
                                          half8& h, half8& l) {
    float v[8] = {a[0], a[1], a[2], a[3], b[0], b[1], b[2], b[3]};
#pragma unroll
    for (int j = 0; j < 8; ++j) {
        const float s = v[j] * 256.0f;
        const _Float16 hh = (_Float16)s;
        const _Float16 ll = (_Float16)(s - (float)hh);
        h[j] = hh; l[j] = ll;
    }
}

// ---------------- pre-split fp32 -> fp16 hi/lo tile images (+ fused norms) ----
// One block per 128-row tile. Output image per (tile, kb): hi[4096], lo[4096]
// halves; slot (r*4+s)*8 holds source k-slot s^SWZ(r) of k-chunk kb.
// This is byte-identical to the LDS image the MFMA kernel wants, so staging
// is a linear global_load_lds.
__global__ void lp_split(const float* __restrict__ src, _Float16* __restrict__ dst,
                         float* __restrict__ ln) {
    const int tile = blockIdx.x;
    const int t    = threadIdx.x;
    const int rlo  = t >> 2;    // 0..63
    const int s    = t & 3;
    const float* srcT = src + (size_t)tile * 128 * DDIM;
    _Float16*    dstT = dst + (size_t)tile * TILE_HALVES;

    float n0 = 0.f, n1 = 0.f;
#pragma unroll
    for (int kb = 0; kb < 8; ++kb) {
#pragma unroll
        for (int sub = 0; sub < 2; ++sub) {
            const int r  = rlo + 64 * sub;
            const int ks = s ^ SWZ(r);
            const float* p = srcT + (size_t)r * DDIM + kb * 32 + ks * 8;
            const f32x4 a = *reinterpret_cast<const f32x4*>(p);
            const f32x4 b = *reinterpret_cast<const f32x4*>(p + 4);
            half8 h, l; cvt_split(a, b, h, l);
            _Float16* base = dstT + kb * KB_HALVES + (r * 4 + s) * 8;
            *reinterpret_cast<half8*>(base)        = h;
            *reinterpret_cast<half8*>(base + 4096) = l;
            const float ss = a[0]*a[0] + a[1]*a[1] + a[2]*a[2] + a[3]*a[3]
                           + b[0]*b[0] + b[1]*b[1] + b[2]*b[2] + b[3]*b[3];
            if (sub == 0) n0 += ss; else n1 += ss;
        }
    }
    if (ln != nullptr) {
        // reduce across the 4 s-lanes of each row group
        n0 += __shfl_xor(n0, 1); n0 += __shfl_xor(n0, 2);
        n1 += __shfl_xor(n1, 1); n1 += __shfl_xor(n1, 2);
        if (s == 0) {
            ln[(size_t)tile * 128 + rlo]      = n0;
            ln[(size_t)tile * 128 + rlo + 64] = n1;
        }
    }
}

// ---------------- async 4KB stage: 256 threads x 16B, linear ----------------
__device__ __forceinline__ void stage4k(_Float16* lds, const _Float16* g, int t) {
    const int wid = t >> 6;
    __builtin_amdgcn_global_load_lds(
        (const __attribute__((address_space(1))) void*)(g + (size_t)t * 8),
        (__attribute__((address_space(3))) void*)(lds + (size_t)wid * 512),
        16, 0, 0);
}

// ---------------- MFMA nearest-neighbor partial (pre-split inputs) ----------
// grid.x: query tiles (BATCH/128), grid.y: lib chunks
// score key (scaled by 2^16) = 65536*ln[l] - 2*acc,  acc = 65536*dot(q,l)
__global__ __launch_bounds__(256, 3)
void lp_nn_mfma2(const _Float16* __restrict__ Qs, const _Float16* __restrict__ Ls,
                 const float* __restrict__ ln, int chunkRows,
                 float* __restrict__ pscore, int* __restrict__ pidx, int nchunks)
{
    __shared__ _Float16 Ah[128 * 32];
    __shared__ _Float16 Al[128 * 32];
    __shared__ _Float16 Bh[128 * 32];
    __shared__ _Float16 Bl[128 * 32];
    __shared__ float xk[2][128];
    __shared__ int   xi[2][128];

    const int t    = threadIdx.x;
    const int wid  = t >> 6, lane = t & 63;
    const int wq   = wid >> 1, wl = wid & 1;      // wave tile: (wq*64, wl*64)
    const int col  = lane & 15, rg = lane >> 4;   // C: col = lane&15, row = rg*4+i
    const int chunkBase = blockIdx.y * chunkRows;

    const _Float16* Qtile = Qs + (size_t)blockIdx.x * TILE_HALVES;

    float bkey[4][4];
    int   bidxr[4][4];
#pragma unroll
    for (int mf = 0; mf < 4; ++mf)
#pragma unroll
        for (int i = 0; i < 4; ++i) { bkey[mf][i] = INF_F; bidxr[mf][i] = 0x7fffffff; }

    for (int lt = 0; lt < chunkRows; lt += 128) {
        const _Float16* Ltile = Ls + (size_t)((chunkBase + lt) >> 7) * TILE_HALVES;

        f32x4 acc[4][4];
#pragma unroll
        for (int mf = 0; mf < 4; ++mf)
#pragma unroll
            for (int nf = 0; nf < 4; ++nf) acc[mf][nf] = (f32x4)(0.f);

        for (int kb = 0; kb < 8; ++kb) {
            const _Float16* Qkb = Qtile + kb * KB_HALVES;
            const _Float16* Lkb = Ltile + kb * KB_HALVES;
            __syncthreads();
            stage4k(Ah,        Qkb,        t);
            stage4k(Ah + 2048, Qkb + 2048, t);
            stage4k(Al,        Qkb + 4096, t);
            stage4k(Al + 2048, Qkb + 6144, t);
            stage4k(Bh,        Lkb,        t);
            stage4k(Bh + 2048, Lkb + 2048, t);
            stage4k(Bl,        Lkb + 4096, t);
            stage4k(Bl + 2048, Lkb + 6144, t);
            __syncthreads();

            half8 ah[4], al[4];
#pragma unroll
            for (int mf = 0; mf < 4; ++mf) {
                const int r = wq * 64 + mf * 16 + col;
                const int s = rg ^ SWZ(r);
                ah[mf] = *reinterpret_cast<const half8*>(&Ah[r * 32 + s * 8]);
                al[mf] = *reinterpret_cast<const half8*>(&Al[r * 32 + s * 8]);
            }
#pragma unroll
            for (int nf = 0; nf < 4; ++nf) {
                const int r = wl * 64 + nf * 16 + col;
                const int s = rg ^ SWZ(r);
                const half8 bh = *reinterpret_cast<const half8*>(&Bh[r * 32 + s * 8]);
                const half8 bl = *reinterpret_cast<const half8*>(&Bl[r * 32 + s * 8]);
#pragma unroll
                for (int mf = 0; mf < 4; ++mf) {
                    acc[mf][nf] = __builtin_amdgcn_mfma_f32_16x16x32_f16(ah[mf], bh, acc[mf][nf], 0, 0, 0);
                    acc[mf][nf] = __builtin_amdgcn_mfma_f32_16x16x32_f16(ah[mf], bl, acc[mf][nf], 0, 0, 0);
                    acc[mf][nf] = __builtin_amdgcn_mfma_f32_16x16x32_f16(al[mf], bh, acc[mf][nf], 0, 0, 0);
                }
            }
        }

        // fold this 128-row lib tile into the running best
#pragma unroll
        for (int nf = 0; nf < 4; ++nf) {
            const int gidx = chunkBase + lt + wl * 64 + nf * 16 + col;
            const float lnv = ln[gidx] * 65536.0f;
#pragma unroll
            for (int mf = 0; mf < 4; ++mf)
#pragma unroll
                for (int i = 0; i < 4; ++i) {
                    const float key = fmaf(-2.f, acc[mf][nf][i], lnv);
                    if (key < bkey[mf][i] || (key == bkey[mf][i] && gidx < bidxr[mf][i])) {
                        bkey[mf][i] = key; bidxr[mf][i] = gidx;
                    }
                }
        }
    }

    // butterfly-reduce across the 16 C-columns (low 4 lane bits)
#pragma unroll
    for (int off = 1; off < 16; off <<= 1) {
#pragma unroll
        for (int mf = 0; mf < 4; ++mf)
#pragma unroll
            for (int i = 0; i < 4; ++i) {
                const float ok = __shfl_xor(bkey[mf][i], off);
                const int   oi = __shfl_xor(bidxr[mf][i], off);
                if (ok < bkey[mf][i] || (ok == bkey[mf][i] && oi < bidxr[mf][i])) {
                    bkey[mf][i] = ok; bidxr[mf][i] = oi;
                }
            }
    }
    // cross-wave combine: waves (wq,0) and (wq,1) cover the same q-rows
    if (col == 0) {
#pragma unroll
        for (int mf = 0; mf < 4; ++mf)
#pragma unroll
            for (int i = 0; i < 4; ++i) {
                const int ql = wq * 64 + mf * 16 + rg * 4 + i;
                xk[wl][ql] = bkey[mf][i];
                xi[wl][ql] = bidxr[mf][i];
            }
    }
    __syncthreads();
    if (t < 128) {
        float bk = xk[0][t]; int bi = xi[0][t];
        const float k2 = xk[1][t]; const int i2 = xi[1][t];
        if (k2 < bk || (k2 == bk && i2 < bi)) { bk = k2; bi = i2; }
        const int q = blockIdx.x * 128 + t;
        pscore[(size_t)q * nchunks + blockIdx.y] = bk;
        pidx  [(size_t)q * nchunks + blockIdx.y] = bi;
    }
}

// ---------------- fallback MFMA kernel (round-3, in-loop split) -------------
__global__ __launch_bounds__(256, 2)
void lp_nn_mfma_fb(const float* __restrict__ Q, const float* __restrict__ L,
                   const float* __restrict__ ln, int chunkRows,
                   float* __restrict__ pscore, int* __restrict__ pidx, int nchunks)
{
    __shared__ _Float16 Ah[128 * 32];
    __shared__ _Float16 Al[128 * 32];
    __shared__ _Float16 Bh[128 * 32];
    __shared__ _Float16 Bl[128 * 32];
    __shared__ float xk[2][128];
    __shared__ int   xi[2][128];

    const int t    = threadIdx.x;
    const int wid  = t >> 6, lane = t & 63;
    const int wq   = wid >> 1, wl = wid & 1;
    const int col  = lane & 15, rg = lane >> 4;
    const int qbase = blockIdx.x * 128;
    const int chunkBase = blockIdx.y * chunkRows;
    const int srow   = t >> 2;
    const int schunk = t & 3;

    float bkey[4][4];
    int   bidxr[4][4];
#pragma unroll
    for (int mf = 0; mf < 4; ++mf)
#pragma unroll
        for (int i = 0; i < 4; ++i) { bkey[mf][i] = INF_F; bidxr[mf][i] = 0x7fffffff; }

    for (int lt = 0; lt < chunkRows; lt += 128) {
        f32x4 acc[4][4];
#pragma unroll
        for (int mf = 0; mf < 4; ++mf)
#pragma unroll
            for (int nf = 0; nf < 4; ++nf) acc[mf][nf] = (f32x4)(0.f);

        for (int kb = 0; kb < DDIM; kb += 32) {
            __syncthreads();
#pragma unroll
            for (int sr = 0; sr < 2; ++sr) {
                const int r = srow + 64 * sr;
                const int s = schunk ^ SWZ(r);
                {
                    const float* src = Q + (size_t)(qbase + r) * DDIM + kb + schunk * 8;
                    const f32x4 a = *reinterpret_cast<const f32x4*>(src);
                    const f32x4 b = *reinterpret_cast<const f32x4*>(src + 4);
                    half8 h, l; cvt_split(a, b, h, l);
                    *reinterpret_cast<half8*>(&Ah[r * 32 + s * 8]) = h;
                    *reinterpret_cast<half8*>(&Al[r * 32 + s * 8]) = l;
                }
                {
                    const float* src = L + (size_t)(chunkBase + lt + r) * DDIM + kb + schunk * 8;
                    const f32x4 a = *reinterpret_cast<const f32x4*>(src);
                    const f32x4 b = *reinterpret_cast<const f32x4*>(src + 4);
                    half8 h, l; cvt_split(a, b, h, l);
                    *reinterpret_cast<half8*>(&Bh[r * 32 + s * 8]) = h;
                    *reinterpret_cast<half8*>(&Bl[r * 32 + s * 8]) = l;
                }
            }
            __syncthreads();

            half8 ah[4], al[4];
#pragma unroll
            for (int mf = 0; mf < 4; ++mf) {
                const int r = wq * 64 + mf * 16 + col;
                const int s = rg ^ SWZ(r);
                ah[mf] = *reinterpret_cast<const half8*>(&Ah[r * 32 + s * 8]);
                al[mf] = *reinterpret_cast<const half8*>(&Al[r * 32 + s * 8]);
            }
#pragma unroll
            for (int nf = 0; nf < 4; ++nf) {
                const int r = wl * 64 + nf * 16 + col;
                const int s = rg ^ SWZ(r);
                const half8 bh = *reinterpret_cast<const half8*>(&Bh[r * 32 + s * 8]);
                const half8 bl = *reinterpret_cast<const half8*>(&Bl[r * 32 + s * 8]);
#pragma unroll
                for (int mf = 0; mf < 4; ++mf) {
                    acc[mf][nf] = __builtin_amdgcn_mfma_f32_16x16x32_f16(ah[mf], bh, acc[mf][nf], 0, 0, 0);
                    acc[mf][nf] = __builtin_amdgcn_mfma_f32_16x16x32_f16(ah[mf], bl, acc[mf][nf], 0, 0, 0);
                    acc[mf][nf] = __builtin_amdgcn_mfma_f32_16x16x32_f16(al[mf], bh, acc[mf][nf], 0, 0, 0);
                }
            }
        }

#pragma unroll
        for (int nf = 0; nf < 4; ++nf) {
            const int gidx = chunkBase + lt + wl * 64 + nf * 16 + col;
            const float lnv = ln[gidx] * 65536.0f;
#pragma unroll
            for (int mf = 0; mf < 4; ++mf)
#pragma unroll
                for (int i = 0; i < 4; ++i) {
                    const float key = fmaf(-2.f, acc[mf][nf][i], lnv);
                    if (key < bkey[mf][i] || (key == bkey[mf][i] && gidx < bidxr[mf][i])) {
                        bkey[mf][i] = key; bidxr[mf][i] = gidx;
                    }
                }
        }
    }

#pragma unroll
    for (int off = 1; off < 16; off <<= 1) {
#pragma unroll
        for (int mf = 0; mf < 4; ++mf)
#pragma unroll
            for (int i = 0; i < 4; ++i) {
                const float ok = __shfl_xor(bkey[mf][i], off);
                const int   oi = __shfl_xor(bidxr[mf][i], off);
                if (ok < bkey[mf][i] || (ok == bkey[mf][i] && oi < bidxr[mf][i])) {
                    bkey[mf][i] = ok; bidxr[mf][i] = oi;
                }
            }
    }
    if (col == 0) {
#pragma unroll
        for (int mf = 0; mf < 4; ++mf)
#pragma unroll
            for (int i = 0; i < 4; ++i) {
                const int ql = wq * 64 + mf * 16 + rg * 4 + i;
                xk[wl][ql] = bkey[mf][i];
                xi[wl][ql] = bidxr[mf][i];
            }
    }
    __syncthreads();
    if (t < 128) {
        float bk = xk[0][t]; int bi = xi[0][t];
        const float k2 = xk[1][t]; const int i2 = xi[1][t];
        if (k2 < bk || (k2 == bk && i2 < bi)) { bk = k2; bi = i2; }
        const int q = qbase + t;
        pscore[(size_t)q * nchunks + blockIdx.y] = bk;
        pidx  [(size_t)q * nchunks + blockIdx.y] = bi;
    }
}

// ---------------- finalize: reduce partials, exact distances, value+grad ----
__global__ void lp_finalize(const float* __restrict__ Q,
                            const float* __restrict__ prevL,
                            const float* __restrict__ reachL,
                            const float* __restrict__ ps_p, const int* __restrict__ pi_p,
                            const float* __restrict__ ps_r, const int* __restrict__ pi_r,
                            float* __restrict__ out)
{
    const int q = blockIdx.x;
    const int lane = threadIdx.x;

    float k1 = (lane < NC_P) ? ps_p[(size_t)q * NC_P + lane] : INF_F;
    int   i1 = (lane < NC_P) ? pi_p[(size_t)q * NC_P + lane] : 0x7fffffff;
#pragma unroll
    for (int off = 32; off > 0; off >>= 1) {
        const float ok = __shfl_xor(k1, off);
        const int   oi = __shfl_xor(i1, off);
        if (ok < k1 || (ok == k1 && oi < i1)) { k1 = ok; i1 = oi; }
    }
    float k2 = (lane < NC_R) ? ps_r[(size_t)q * NC_R + lane] : INF_F;
    int   i2 = (lane < NC_R) ? pi_r[(size_t)q * NC_R + lane] : 0x7fffffff;
#pragma unroll
    for (int off = 32; off > 0; off >>= 1) {
        const float ok = __shfl_xor(k2, off);
        const int   oi = __shfl_xor(i2, off);
        if (ok < k2 || (ok == k2 && oi < i2)) { k2 = ok; i2 = oi; }
    }

    const float4 tv = reinterpret_cast<const float4*>(Q      + (size_t)q  * DDIM)[lane];
    const float4 e1 = reinterpret_cast<const float4*>(prevL  + (size_t)i1 * DDIM)[lane];
    const float4 e2 = reinterpret_cast<const float4*>(reachL + (size_t)i2 * DDIM)[lane];
    const float4 d1 = {tv.x - e1.x, tv.y - e1.y, tv.z - e1.z, tv.w - e1.w};
    const float4 d2 = {tv.x - e2.x, tv.y - e2.y, tv.z - e2.z, tv.w - e2.w};
    float s1 = d1.x * d1.x + d1.y * d1.y + d1.z * d1.z + d1.w * d1.w;
    float s2 = d2.x * d2.x + d2.y * d2.y + d2.z * d2.z + d2.w * d2.w;
#pragma unroll
    for (int off = 32; off > 0; off >>= 1) {
        s1 += __shfl_xor(s1, off);
        s2 += __shfl_xor(s2, off);
    }
    const float r1 = sqrtf(s1), r2 = sqrtf(s2);
    float4 g;
    g.x = d1.x / r1 - d2.x / r2;
    g.y = d1.y / r1 - d2.y / r2;
    g.z = d1.z / r1 - d2.z / r2;
    g.w = d1.w / r1 - d2.w / r2;
    reinterpret_cast<float4*>(out + BATCH + (size_t)q * DDIM)[lane] = g;
    if (lane == 0) out[q] = r1 - r2;
}

extern "C" void kernel_launch(void* const* d_in, const int* in_sizes, int n_in,
                              void* d_out, int out_size, void* d_ws, size_t ws_size,
                              hipStream_t stream) {
    const float* target_lib  = (const float*)d_in[0];
    const float* reached_lib = (const float*)d_in[1];
    const float* Qp     = target_lib  + (size_t)NPREV * DDIM;  // targets
    const float* prevL  = reached_lib;                          // prev
    const float* reachL = reached_lib + (size_t)NPREV * DDIM;  // reached

    float* ws     = (float*)d_ws;
    float* ln_all = ws;                                   // 65536 f = 262144 B
    float* ps_p   = ln_all + NTOT;                        // 2048*31 f
    float* ps_r   = ps_p + (size_t)BATCH * NC_P;          // 2048*16 f
    int*   pi_p   = (int*)(ps_r + (size_t)BATCH * NC_R);
    int*   pi_r   = pi_p + (size_t)BATCH * NC_P;
    _Float16* Qsp = (_Float16*)(pi_r + (size_t)BATCH * NC_R);          // 2 MB
    _Float16* Lsp = Qsp + (size_t)(BATCH / 128) * TILE_HALVES;         // 64 MB
    float* out    = (float*)d_out;

    const size_t need = (size_t)(ln_all ? 0 : 0) + 1032192u
                      + (size_t)(BATCH / 128) * TILE_HALVES * 2
                      + (size_t)(NTOT / 128) * TILE_HALVES * 2;

    if (ws_size >= need) {
        // fast path: pre-split (+fused norms), then gload_lds-staged MFMA
        lp_split<<<NTOT / 128, 256, 0, stream>>>(reached_lib, Lsp, ln_all);
        lp_split<<<BATCH / 128, 256, 0, stream>>>(Qp, Qsp, nullptr);
        lp_nn_mfma2<<<dim3(BATCH / 128, NC_P), 256, 0, stream>>>(
            Qsp, Lsp, ln_all, CHUNK_P, ps_p, pi_p, NC_P);
        lp_nn_mfma2<<<dim3(BATCH / 128, NC_R), 256, 0, stream>>>(
            Qsp, Lsp + (size_t)(NPREV / 128) * TILE_HALVES,
            ln_all + NPREV, CHUNK_R, ps_r, pi_r, NC_R);
    } else {
        // fallback: round-3 path (in-loop split)
        lp_norms<<<NTOT / 4, 256, 0, stream>>>(reached_lib, ln_all);
        lp_nn_mfma_fb<<<dim3(BATCH / 128, NC_P), 256, 0, stream>>>(
            Qp, prevL, ln_all, CHUNK_P, ps_p, pi_p, NC_P);
        lp_nn_mfma_fb<<<dim3(BATCH / 128, NC_R), 256, 0, stream>>>(
            Qp, reachL, ln_all + NPREV, CHUNK_R, ps_r, pi_r, NC_R);
    }
    lp_finalize<<<BATCH, 64, 0, stream>>>(Qp, prevL, reachL, ps_p, pi_p, ps_r, pi_r, out);
}

// Round 5
// 262.205 us; speedup vs baseline: 1.6146x; 1.6146x over previous
//
#include <hip/hip_runtime.h>
#include <math.h>

#define NTOT   65536
#define DDIM   256
#define BATCH  2048
#define NPREV  (NTOT - BATCH)   // 63488

#define NC_P 31
#define CHUNK_P 2048            // 31 * 2048 = 63488
#define NC_R 16
#define CHUNK_R 128             // 16 * 128 = 2048

#define INF_F 3.402823466e+38f
#define SWZ(r) ((((r) & 3)) ^ ((((r) >> 2) & 3)))

typedef float  f32x4 __attribute__((ext_vector_type(4)));
typedef _Float16 half8 __attribute__((ext_vector_type(8)));

// halves per 128-row tile image: 128 r * 256 k * 2 (hi,lo) = 65536
#define TILE_HALVES 65536
// halves per kb block within a tile: 2(hl) * 128 r * 4 s * 8 = 8192
#define KB_HALVES   8192

// ---------------- row norms (standalone, used by fallback) ----------------
__global__ void lp_norms(const float* __restrict__ lib, float* __restrict__ ln) {
    const int row  = blockIdx.x * 4 + (threadIdx.x >> 6);
    const int lane = threadIdx.x & 63;
    const float4 v = reinterpret_cast<const float4*>(lib + (size_t)row * DDIM)[lane];
    float s = v.x * v.x + v.y * v.y + v.z * v.z + v.w * v.w;
#pragma unroll
    for (int off = 32; off > 0; off >>= 1) s += __shfl_down(s, off);
    if (lane == 0) ln[row] = s;
}

// fp16 split with x256 scaling (keeps residual out of subnormal range)
__device__ __forceinline__ void cvt_split(const f32x4 a, const f32x4 b,
                                          half8& h, half8& l) {
    float v[8] = {a[0], a[1], a[2], a[3], b[0], b[1], b[2], b[3]};
#pragma unroll
    for (int j = 0; j < 8; ++j) {
        const float s = v[j] * 256.0f;
        const _Float16 hh = (_Float16)s;
        const _Float16 ll = (_Float16)(s - (float)hh);
        h[j] = hh; l[j] = ll;
    }
}

// ---------------- pre-split fp32 -> fp16 hi/lo tile images (+ fused norms) ----
__global__ void lp_split(const float* __restrict__ src, _Float16* __restrict__ dst,
                         float* __restrict__ ln) {
    const int tile = blockIdx.x;
    const int t    = threadIdx.x;
    const int rlo  = t >> 2;    // 0..63
    const int s    = t & 3;
    const float* srcT = src + (size_t)tile * 128 * DDIM;
    _Float16*    dstT = dst + (size_t)tile * TILE_HALVES;

    float n0 = 0.f, n1 = 0.f;
#pragma unroll
    for (int kb = 0; kb < 8; ++kb) {
#pragma unroll
        for (int sub = 0; sub < 2; ++sub) {
            const int r  = rlo + 64 * sub;
            const int ks = s ^ SWZ(r);
            const float* p = srcT + (size_t)r * DDIM + kb * 32 + ks * 8;
            const f32x4 a = *reinterpret_cast<const f32x4*>(p);
            const f32x4 b = *reinterpret_cast<const f32x4*>(p + 4);
            half8 h, l; cvt_split(a, b, h, l);
            _Float16* base = dstT + kb * KB_HALVES + (r * 4 + s) * 8;
            *reinterpret_cast<half8*>(base)        = h;
            *reinterpret_cast<half8*>(base + 4096) = l;
            const float ss = a[0]*a[0] + a[1]*a[1] + a[2]*a[2] + a[3]*a[3]
                           + b[0]*b[0] + b[1]*b[1] + b[2]*b[2] + b[3]*b[3];
            if (sub == 0) n0 += ss; else n1 += ss;
        }
    }
    if (ln != nullptr) {
        n0 += __shfl_xor(n0, 1); n0 += __shfl_xor(n0, 2);
        n1 += __shfl_xor(n1, 1); n1 += __shfl_xor(n1, 2);
        if (s == 0) {
            ln[(size_t)tile * 128 + rlo]      = n0;
            ln[(size_t)tile * 128 + rlo + 64] = n1;
        }
    }
}

// ---------------- async 4KB stage: 256 threads x 16B, linear ----------------
__device__ __forceinline__ void stage4k(_Float16* lds, const _Float16* g, int t) {
    const int wid = t >> 6;
    __builtin_amdgcn_global_load_lds(
        (const __attribute__((address_space(1))) void*)(g + (size_t)t * 8),
        (__attribute__((address_space(3))) void*)(lds + (size_t)wid * 512),
        16, 0, 0);
}

// ---------------- MFMA NN partial: XCD-grouped, double-buffered -------------
// Linear grid of 16*nchunks blocks; XCD remap groups chunk-sharing blocks on
// one XCD (hid%8 -> XCD round-robin assumption, bijective since nwg%8==0).
__global__ __launch_bounds__(256, 2)
void lp_nn_mfma3(const _Float16* __restrict__ Qs, const _Float16* __restrict__ Ls,
                 const float* __restrict__ ln, int chunkRows,
                 float* __restrict__ pscore, int* __restrict__ pidx, int nchunks)
{
    __shared__ _Float16 B0[4][4096];   // Ah, Al, Bh, Bl
    __shared__ _Float16 B1[4][4096];
    __shared__ float xk[2][128];
    __shared__ int   xi[2][128];

    const int nwg  = 16 * nchunks;
    const int hid  = blockIdx.x;
    const int work = (hid & 7) * (nwg >> 3) + (hid >> 3);
    const int bx   = work & 15;     // query tile
    const int by   = work >> 4;     // lib chunk

    const int t    = threadIdx.x;
    const int wid  = t >> 6, lane = t & 63;
    const int wq   = wid >> 1, wl = wid & 1;
    const int col  = lane & 15, rg = lane >> 4;
    const int chunkBase = by * chunkRows;

    const _Float16* Qtile = Qs + (size_t)bx * TILE_HALVES;
    const _Float16* Lbase = Ls + (size_t)(chunkBase >> 7) * TILE_HALVES;
    const int NSTEP = (chunkRows >> 7) * 8;   // multiple of 8 (even)

    float bkey[4][4];
    int   bidxr[4][4];
    f32x4 acc[4][4];
#pragma unroll
    for (int mf = 0; mf < 4; ++mf)
#pragma unroll
        for (int i = 0; i < 4; ++i) {
            bkey[mf][i] = INF_F; bidxr[mf][i] = 0x7fffffff;
            acc[mf][i] = (f32x4)(0.f);
        }

    auto stage = [&](_Float16 (&dst)[4][4096], int s) {
        const int kb = s & 7, lt = s >> 3;
        const _Float16* Qkb = Qtile + kb * KB_HALVES;
        const _Float16* Lkb = Lbase + (size_t)lt * TILE_HALVES + kb * KB_HALVES;
        stage4k(&dst[0][0],    Qkb,        t);
        stage4k(&dst[0][2048], Qkb + 2048, t);
        stage4k(&dst[1][0],    Qkb + 4096, t);
        stage4k(&dst[1][2048], Qkb + 6144, t);
        stage4k(&dst[2][0],    Lkb,        t);
        stage4k(&dst[2][2048], Lkb + 2048, t);
        stage4k(&dst[3][0],    Lkb + 4096, t);
        stage4k(&dst[3][2048], Lkb + 6144, t);
    };

    auto compute = [&](const _Float16 (&buf)[4][4096], int s) {
        half8 ah[4], al[4];
#pragma unroll
        for (int mf = 0; mf < 4; ++mf) {
            const int r = wq * 64 + mf * 16 + col;
            const int sw = rg ^ SWZ(r);
            ah[mf] = *reinterpret_cast<const half8*>(&buf[0][r * 32 + sw * 8]);
            al[mf] = *reinterpret_cast<const half8*>(&buf[1][r * 32 + sw * 8]);
        }
#pragma unroll
        for (int nf = 0; nf < 4; ++nf) {
            const int r = wl * 64 + nf * 16 + col;
            const int sw = rg ^ SWZ(r);
            const half8 bh = *reinterpret_cast<const half8*>(&buf[2][r * 32 + sw * 8]);
            const half8 bl = *reinterpret_cast<const half8*>(&buf[3][r * 32 + sw * 8]);
#pragma unroll
            for (int mf = 0; mf < 4; ++mf) {
                acc[mf][nf] = __builtin_amdgcn_mfma_f32_16x16x32_f16(ah[mf], bh, acc[mf][nf], 0, 0, 0);
                acc[mf][nf] = __builtin_amdgcn_mfma_f32_16x16x32_f16(ah[mf], bl, acc[mf][nf], 0, 0, 0);
                acc[mf][nf] = __builtin_amdgcn_mfma_f32_16x16x32_f16(al[mf], bh, acc[mf][nf], 0, 0, 0);
            }
        }
        if ((s & 7) == 7) {
            const int ltbase = chunkBase + ((s >> 3) << 7);
#pragma unroll
            for (int nf = 0; nf < 4; ++nf) {
                const int gidx = ltbase + wl * 64 + nf * 16 + col;
                const float lnv = ln[gidx] * 65536.0f;
#pragma unroll
                for (int mf = 0; mf < 4; ++mf)
#pragma unroll
                    for (int i = 0; i < 4; ++i) {
                        const float key = fmaf(-2.f, acc[mf][nf][i], lnv);
                        if (key < bkey[mf][i] || (key == bkey[mf][i] && gidx < bidxr[mf][i])) {
                            bkey[mf][i] = key; bidxr[mf][i] = gidx;
                        }
                        acc[mf][nf][i] = 0.f;
                    }
            }
        }
    };

    stage(B0, 0);
    __syncthreads();
    for (int s = 0; s < NSTEP; s += 2) {
        stage(B1, s + 1);                       // prefetch s+1 while computing s
        compute(B0, s);
        __syncthreads();                        // drains prefetch (vmcnt 0)
        if (s + 2 < NSTEP) stage(B0, s + 2);    // prefetch s+2 while computing s+1
        compute(B1, s + 1);
        __syncthreads();
    }

    // butterfly-reduce across the 16 C-columns
#pragma unroll
    for (int off = 1; off < 16; off <<= 1) {
#pragma unroll
        for (int mf = 0; mf < 4; ++mf)
#pragma unroll
            for (int i = 0; i < 4; ++i) {
                const float ok = __shfl_xor(bkey[mf][i], off);
                const int   oi = __shfl_xor(bidxr[mf][i], off);
                if (ok < bkey[mf][i] || (ok == bkey[mf][i] && oi < bidxr[mf][i])) {
                    bkey[mf][i] = ok; bidxr[mf][i] = oi;
                }
            }
    }
    // cross-wave combine: waves (wq,0) and (wq,1) cover the same q-rows
    if (col == 0) {
#pragma unroll
        for (int mf = 0; mf < 4; ++mf)
#pragma unroll
            for (int i = 0; i < 4; ++i) {
                const int ql = wq * 64 + mf * 16 + rg * 4 + i;
                xk[wl][ql] = bkey[mf][i];
                xi[wl][ql] = bidxr[mf][i];
            }
    }
    __syncthreads();
    if (t < 128) {
        float bk = xk[0][t]; int bi = xi[0][t];
        const float k2 = xk[1][t]; const int i2 = xi[1][t];
        if (k2 < bk || (k2 == bk && i2 < bi)) { bk = k2; bi = i2; }
        const int q = bx * 128 + t;
        pscore[(size_t)q * nchunks + by] = bk;
        pidx  [(size_t)q * nchunks + by] = bi;
    }
}

// ---------------- fallback MFMA kernel (round-3, in-loop split) -------------
__global__ __launch_bounds__(256, 2)
void lp_nn_mfma_fb(const float* __restrict__ Q, const float* __restrict__ L,
                   const float* __restrict__ ln, int chunkRows,
                   float* __restrict__ pscore, int* __restrict__ pidx, int nchunks)
{
    __shared__ _Float16 Ah[128 * 32];
    __shared__ _Float16 Al[128 * 32];
    __shared__ _Float16 Bh[128 * 32];
    __shared__ _Float16 Bl[128 * 32];
    __shared__ float xk[2][128];
    __shared__ int   xi[2][128];

    const int t    = threadIdx.x;
    const int wid  = t >> 6, lane = t & 63;
    const int wq   = wid >> 1, wl = wid & 1;
    const int col  = lane & 15, rg = lane >> 4;
    const int qbase = blockIdx.x * 128;
    const int chunkBase = blockIdx.y * chunkRows;
    const int srow   = t >> 2;
    const int schunk = t & 3;

    float bkey[4][4];
    int   bidxr[4][4];
#pragma unroll
    for (int mf = 0; mf < 4; ++mf)
#pragma unroll
        for (int i = 0; i < 4; ++i) { bkey[mf][i] = INF_F; bidxr[mf][i] = 0x7fffffff; }

    for (int lt = 0; lt < chunkRows; lt += 128) {
        f32x4 acc[4][4];
#pragma unroll
        for (int mf = 0; mf < 4; ++mf)
#pragma unroll
            for (int nf = 0; nf < 4; ++nf) acc[mf][nf] = (f32x4)(0.f);

        for (int kb = 0; kb < DDIM; kb += 32) {
            __syncthreads();
#pragma unroll
            for (int sr = 0; sr < 2; ++sr) {
                const int r = srow + 64 * sr;
                const int s = schunk ^ SWZ(r);
                {
                    const float* src = Q + (size_t)(qbase + r) * DDIM + kb + schunk * 8;
                    const f32x4 a = *reinterpret_cast<const f32x4*>(src);
                    const f32x4 b = *reinterpret_cast<const f32x4*>(src + 4);
                    half8 h, l; cvt_split(a, b, h, l);
                    *reinterpret_cast<half8*>(&Ah[r * 32 + s * 8]) = h;
                    *reinterpret_cast<half8*>(&Al[r * 32 + s * 8]) = l;
                }
                {
                    const float* src = L + (size_t)(chunkBase + lt + r) * DDIM + kb + schunk * 8;
                    const f32x4 a = *reinterpret_cast<const f32x4*>(src);
                    const f32x4 b = *reinterpret_cast<const f32x4*>(src + 4);
                    half8 h, l; cvt_split(a, b, h, l);
                    *reinterpret_cast<half8*>(&Bh[r * 32 + s * 8]) = h;
                    *reinterpret_cast<half8*>(&Bl[r * 32 + s * 8]) = l;
                }
            }
            __syncthreads();

            half8 ah[4], al[4];
#pragma unroll
            for (int mf = 0; mf < 4; ++mf) {
                const int r = wq * 64 + mf * 16 + col;
                const int s = rg ^ SWZ(r);
                ah[mf] = *reinterpret_cast<const half8*>(&Ah[r * 32 + s * 8]);
                al[mf] = *reinterpret_cast<const half8*>(&Al[r * 32 + s * 8]);
            }
#pragma unroll
            for (int nf = 0; nf < 4; ++nf) {
                const int r = wl * 64 + nf * 16 + col;
                const int s = rg ^ SWZ(r);
                const half8 bh = *reinterpret_cast<const half8*>(&Bh[r * 32 + s * 8]);
                const half8 bl = *reinterpret_cast<const half8*>(&Bl[r * 32 + s * 8]);
#pragma unroll
                for (int mf = 0; mf < 4; ++mf) {
                    acc[mf][nf] = __builtin_amdgcn_mfma_f32_16x16x32_f16(ah[mf], bh, acc[mf][nf], 0, 0, 0);
                    acc[mf][nf] = __builtin_amdgcn_mfma_f32_16x16x32_f16(ah[mf], bl, acc[mf][nf], 0, 0, 0);
                    acc[mf][nf] = __builtin_amdgcn_mfma_f32_16x16x32_f16(al[mf], bh, acc[mf][nf], 0, 0, 0);
                }
            }
        }

#pragma unroll
        for (int nf = 0; nf < 4; ++nf) {
            const int gidx = chunkBase + lt + wl * 64 + nf * 16 + col;
            const float lnv = ln[gidx] * 65536.0f;
#pragma unroll
            for (int mf = 0; mf < 4; ++mf)
#pragma unroll
                for (int i = 0; i < 4; ++i) {
                    const float key = fmaf(-2.f, acc[mf][nf][i], lnv);
                    if (key < bkey[mf][i] || (key == bkey[mf][i] && gidx < bidxr[mf][i])) {
                        bkey[mf][i] = key; bidxr[mf][i] = gidx;
                    }
                }
        }
    }

#pragma unroll
    for (int off = 1; off < 16; off <<= 1) {
#pragma unroll
        for (int mf = 0; mf < 4; ++mf)
#pragma unroll
            for (int i = 0; i < 4; ++i) {
                const float ok = __shfl_xor(bkey[mf][i], off);
                const int   oi = __shfl_xor(bidxr[mf][i], off);
                if (ok < bkey[mf][i] || (ok == bkey[mf][i] && oi < bidxr[mf][i])) {
                    bkey[mf][i] = ok; bidxr[mf][i] = oi;
                }
            }
    }
    if (col == 0) {
#pragma unroll
        for (int mf = 0; mf < 4; ++mf)
#pragma unroll
            for (int i = 0; i < 4; ++i) {
                const int ql = wq * 64 + mf * 16 + rg * 4 + i;
                xk[wl][ql] = bkey[mf][i];
                xi[wl][ql] = bidxr[mf][i];
            }
    }
    __syncthreads();
    if (t < 128) {
        float bk = xk[0][t]; int bi = xi[0][t];
        const float k2 = xk[1][t]; const int i2 = xi[1][t];
        if (k2 < bk || (k2 == bk && i2 < bi)) { bk = k2; bi = i2; }
        const int q = qbase + t;
        pscore[(size_t)q * nchunks + blockIdx.y] = bk;
        pidx  [(size_t)q * nchunks + blockIdx.y] = bi;
    }
}

// ---------------- finalize: reduce partials, exact distances, value+grad ----
__global__ void lp_finalize(const float* __restrict__ Q,
                            const float* __restrict__ prevL,
                            const float* __restrict__ reachL,
                            const float* __restrict__ ps_p, const int* __restrict__ pi_p,
                            const float* __restrict__ ps_r, const int* __restrict__ pi_r,
                            float* __restrict__ out)
{
    const int q = blockIdx.x;
    const int lane = threadIdx.x;

    float k1 = (lane < NC_P) ? ps_p[(size_t)q * NC_P + lane] : INF_F;
    int   i1 = (lane < NC_P) ? pi_p[(size_t)q * NC_P + lane] : 0x7fffffff;
#pragma unroll
    for (int off = 32; off > 0; off >>= 1) {
        const float ok = __shfl_xor(k1, off);
        const int   oi = __shfl_xor(i1, off);
        if (ok < k1 || (ok == k1 && oi < i1)) { k1 = ok; i1 = oi; }
    }
    float k2 = (lane < NC_R) ? ps_r[(size_t)q * NC_R + lane] : INF_F;
    int   i2 = (lane < NC_R) ? pi_r[(size_t)q * NC_R + lane] : 0x7fffffff;
#pragma unroll
    for (int off = 32; off > 0; off >>= 1) {
        const float ok = __shfl_xor(k2, off);
        const int   oi = __shfl_xor(i2, off);
        if (ok < k2 || (ok == k2 && oi < i2)) { k2 = ok; i2 = oi; }
    }

    const float4 tv = reinterpret_cast<const float4*>(Q      + (size_t)q  * DDIM)[lane];
    const float4 e1 = reinterpret_cast<const float4*>(prevL  + (size_t)i1 * DDIM)[lane];
    const float4 e2 = reinterpret_cast<const float4*>(reachL + (size_t)i2 * DDIM)[lane];
    const float4 d1 = {tv.x - e1.x, tv.y - e1.y, tv.z - e1.z, tv.w - e1.w};
    const float4 d2 = {tv.x - e2.x, tv.y - e2.y, tv.z - e2.z, tv.w - e2.w};
    float s1 = d1.x * d1.x + d1.y * d1.y + d1.z * d1.z + d1.w * d1.w;
    float s2 = d2.x * d2.x + d2.y * d2.y + d2.z * d2.z + d2.w * d2.w;
#pragma unroll
    for (int off = 32; off > 0; off >>= 1) {
        s1 += __shfl_xor(s1, off);
        s2 += __shfl_xor(s2, off);
    }
    const float r1 = sqrtf(s1), r2 = sqrtf(s2);
    float4 g;
    g.x = d1.x / r1 - d2.x / r2;
    g.y = d1.y / r1 - d2.y / r2;
    g.z = d1.z / r1 - d2.z / r2;
    g.w = d1.w / r1 - d2.w / r2;
    reinterpret_cast<float4*>(out + BATCH + (size_t)q * DDIM)[lane] = g;
    if (lane == 0) out[q] = r1 - r2;
}

extern "C" void kernel_launch(void* const* d_in, const int* in_sizes, int n_in,
                              void* d_out, int out_size, void* d_ws, size_t ws_size,
                              hipStream_t stream) {
    const float* target_lib  = (const float*)d_in[0];
    const float* reached_lib = (const float*)d_in[1];
    const float* Qp     = target_lib  + (size_t)NPREV * DDIM;  // targets
    const float* prevL  = reached_lib;                          // prev
    const float* reachL = reached_lib + (size_t)NPREV * DDIM;  // reached

    float* ws     = (float*)d_ws;
    float* ln_all = ws;                                   // 65536 f
    float* ps_p   = ln_all + NTOT;                        // 2048*31 f
    float* ps_r   = ps_p + (size_t)BATCH * NC_P;          // 2048*16 f
    int*   pi_p   = (int*)(ps_r + (size_t)BATCH * NC_R);
    int*   pi_r   = pi_p + (size_t)BATCH * NC_P;
    _Float16* Qsp = (_Float16*)(pi_r + (size_t)BATCH * NC_R);          // 2 MB
    _Float16* Lsp = Qsp + (size_t)(BATCH / 128) * TILE_HALVES;         // 64 MB
    float* out    = (float*)d_out;

    const size_t need = 1032192u
                      + (size_t)(BATCH / 128) * TILE_HALVES * 2
                      + (size_t)(NTOT / 128) * TILE_HALVES * 2;

    if (ws_size >= need) {
        lp_split<<<NTOT / 128, 256, 0, stream>>>(reached_lib, Lsp, ln_all);
        lp_split<<<BATCH / 128, 256, 0, stream>>>(Qp, Qsp, nullptr);
        lp_nn_mfma3<<<16 * NC_P, 256, 0, stream>>>(
            Qsp, Lsp, ln_all, CHUNK_P, ps_p, pi_p, NC_P);
        lp_nn_mfma3<<<16 * NC_R, 256, 0, stream>>>(
            Qsp, Lsp + (size_t)(NPREV / 128) * TILE_HALVES,
            ln_all + NPREV, CHUNK_R, ps_r, pi_r, NC_R);
    } else {
        lp_norms<<<NTOT / 4, 256, 0, stream>>>(reached_lib, ln_all);
        lp_nn_mfma_fb<<<dim3(BATCH / 128, NC_P), 256, 0, stream>>>(
            Qp, prevL, ln_all, CHUNK_P, ps_p, pi_p, NC_P);
        lp_nn_mfma_fb<<<dim3(BATCH / 128, NC_R), 256, 0, stream>>>(
            Qp, reachL, ln_all + NPREV, CHUNK_R, ps_r, pi_r, NC_R);
    }
    lp_finalize<<<BATCH, 64, 0, stream>>>(Qp, prevL, reachL, ps_p, pi_p, ps_r, pi_r, out);
}